// Round 1
// 81.365 us; speedup vs baseline: 1.1204x; 1.1204x over previous
//
#include <hip/hip_runtime.h>
#include <stdint.h>

#define SC 192      // coarse samples (128 + 64)
#define SF 128      // fine (importance) samples
#define NT 128      // threads per block = 2 waves

// LDS weight-image offsets (floats)
#define WD1   0     // 96  (3x32 row-major)
#define BD1   96    // 32
#define WD2   128   // 32
#define BD2   160   // 1
#define BC2   161   // 3
#define NV4   164   // 32 x float4: (bc1[n], Wc1[32][n], Wc1[33][n], Wc1[34][n])
#define W24   292   // 32 x float4: (Wc2[n][0],[1],[2], 0)
#define SWTOT 420   // floats (105 float4s)

#define WS_FRAG_OFF 2048    // byte offset of Wc1 fp16 A-frags in d_ws
#define WS_NEED     4096

#define HSTRIDE 40  // ushort stride for H rows (80 B rows -> bank-friendly)
#define RGBS 4

using half8 = __attribute__((ext_vector_type(8))) _Float16;
using f32x4 = __attribute__((ext_vector_type(4))) float;

__device__ __forceinline__ float zlog_c(int t) {
  return (t < 128) ? (-1.0f + (float)t * 0.0078125f)
                   : ((float)(t - 128) * 0.015625f);
}
__device__ __forceinline__ float delta_c(int t) {
  if (t >= SC - 1) return 0.0f;
  return zlog_c(t + 1) - zlog_c(t);
}

__device__ __forceinline__ float fast_rcp(float x) { return __builtin_amdgcn_rcpf(x); }
__device__ __forceinline__ float fast_rsq(float x) { return __builtin_amdgcn_rsqf(x); }
__device__ __forceinline__ float exp10_f(float x) { return __expf(x * 2.30258509299f); }
__device__ __forceinline__ float softplus_f(float x) {
  return fmaxf(x, 0.0f) + __logf(1.0f + __expf(-fabsf(x)));
}

// fp16 helpers: pk2h = 1 HW instr (v_cvt_pkrtz_f16_f32); f2h = RTN scalar convert
__device__ __forceinline__ uint32_t pk2h(float a, float b) {
  auto p = __builtin_amdgcn_cvt_pkrtz(a, b);
  uint32_t u; __builtin_memcpy(&u, &p, 4); return u;
}
__device__ __forceinline__ unsigned short f2h(float f) {
  _Float16 h = (_Float16)f;
  unsigned short us; __builtin_memcpy(&us, &h, 2); return us;
}

__device__ __forceinline__ float4 ldsf4(const float* p) { return *(const float4*)p; }

// JAX threefry2x32 with key = (0, 42)
__device__ __forceinline__ void threefry2x32_k42(uint32_t& x0, uint32_t& x1) {
  const uint32_t ks0 = 0u, ks1 = 42u;
  const uint32_t ks2 = ks0 ^ ks1 ^ 0x1BD11BDAu;
  const uint32_t ks[3] = {ks0, ks1, ks2};
  const int rot[2][4] = {{13, 15, 26, 6}, {17, 29, 16, 24}};
  x0 += ks[0];
  x1 += ks[1];
#pragma unroll
  for (int i = 0; i < 5; ++i) {
#pragma unroll
    for (int j = 0; j < 4; ++j) {
      x0 += x1;
      const int r = rot[i & 1][j];
      x1 = (x1 << r) | (x1 >> (32 - r));
      x1 ^= x0;
    }
    x0 += ks[(i + 1) % 3];
    x1 += ks[(i + 2) % 3] + (uint32_t)(i + 1);
  }
}

__device__ __forceinline__ float wave_scan_mul(float v, int lane) {
#pragma unroll
  for (int d = 1; d < 64; d <<= 1) {
    float o = __shfl_up(v, d, 64);
    if (lane >= d) v *= o;
  }
  return v;
}
__device__ __forceinline__ float wave_scan_add(float v, int lane) {
#pragma unroll
  for (int d = 1; d < 64; d <<= 1) {
    float o = __shfl_up(v, d, 64);
    if (lane >= d) v += o;
  }
  return v;
}

// ---- pre-pack kernel: weight image + fp16 Wc1 A-frags (identical for all blocks) ----
__global__ __launch_bounds__(NT) void pack_weights(
    const float* __restrict__ Wd1, const float* __restrict__ bd1,
    const float* __restrict__ Wd2, const float* __restrict__ bd2,
    const float* __restrict__ Wc1, const float* __restrict__ bc1,
    const float* __restrict__ Wc2, const float* __restrict__ bc2,
    float* __restrict__ wsf) {
  const int t = threadIdx.x;
  for (int i = t; i < 96; i += NT) wsf[WD1 + i] = Wd1[i];
  for (int i = t; i < 32; i += NT) { wsf[BD1 + i] = bd1[i]; wsf[WD2 + i] = Wd2[i]; }
  if (t == 0) {
    wsf[BD2] = bd2[0];
    wsf[BC2 + 0] = bc2[0]; wsf[BC2 + 1] = bc2[1]; wsf[BC2 + 2] = bc2[2];
  }
  if (t < 32) {
    wsf[NV4 + t * 4 + 0] = bc1[t];
    wsf[NV4 + t * 4 + 1] = Wc1[32 * 32 + t];
    wsf[NV4 + t * 4 + 2] = Wc1[33 * 32 + t];
    wsf[NV4 + t * 4 + 3] = Wc1[34 * 32 + t];
    wsf[W24 + t * 4 + 0] = Wc2[t * 3 + 0];
    wsf[W24 + t * 4 + 1] = Wc2[t * 3 + 1];
    wsf[W24 + t * 4 + 2] = Wc2[t * 3 + 2];
    wsf[W24 + t * 4 + 3] = 0.0f;
  }
  // Wc1[0:32][:] fp16 A-frags: frag[lane*2 + nt]; A[m=n][k], lane: n=nt*16+(lane&15), k=quad*8+j
  if (t < 64) {
    const int q_s = t >> 4;
    uint4* frag = (uint4*)((char*)wsf + WS_FRAG_OFF);
#pragma unroll
    for (int nt = 0; nt < 2; ++nt) {
      const int n_s = nt * 16 + (t & 15);
      uint32_t hw[4];
#pragma unroll
      for (int j2 = 0; j2 < 4; ++j2) {
        const int k = q_s * 8 + j2 * 2;
        hw[j2] = (uint32_t)f2h(Wc1[k * 32 + n_s])
               | ((uint32_t)f2h(Wc1[(k + 1) * 32 + n_s]) << 16);
      }
      frag[t * 2 + nt] = make_uint4(hw[0], hw[1], hw[2], hw[3]);
    }
  }
}

template <bool USE_WS>
__global__ __launch_bounds__(NT) void nerf_fwd(
    const float* __restrict__ hh, const float* __restrict__ ww,
    const float* __restrict__ K, const float* __restrict__ E,
    const float* __restrict__ bg,
    const float* __restrict__ Wd1, const float* __restrict__ bd1,
    const float* __restrict__ Wd2, const float* __restrict__ bd2,
    const float* __restrict__ Wc1, const float* __restrict__ bc1,
    const float* __restrict__ Wc2, const float* __restrict__ bc2,
    const float* __restrict__ wsf,
    float* __restrict__ out, int n_rays) {
  const int ray = blockIdx.x;
  const int t = threadIdx.x;
  const int lane = t & 63;
  const int wv = t >> 6;   // 0 or 1
  const int quad = lane >> 4;

  __shared__ __align__(16) float sw[SWTOT];
  // per-ray factorized density-MLP coefficients: A = o@Wd1, B = d@Wd1
  __shared__ __align__(16) float s_A[32];
  __shared__ __align__(16) float s_B[32];
  // phase-union: coarse {s_w, s_cdf} then fine H (fp16)
  __shared__ __align__(16) unsigned char u_buf[SF * HSTRIDE * 2];  // 10240 B
  float* const s_w   = (float*)u_buf;
  float* const s_cdf = (float*)(u_buf + 768);
  unsigned short* const s_hf = (unsigned short*)u_buf;
  __shared__ float s_rgb[SF * RGBS];
  __shared__ float s_zlf[SF];
  __shared__ float s_tot[8];
  __shared__ float s_red[16];

  // ---- stage weight image into LDS ----
  if constexpr (USE_WS) {
    const float4* wsrc = (const float4*)wsf;
    float4* sdst = (float4*)sw;
    for (int i = t; i < SWTOT / 4; i += NT) sdst[i] = wsrc[i];
  } else {
    for (int i = t; i < 96; i += NT) sw[WD1 + i] = Wd1[i];
    for (int i = t; i < 32; i += NT) { sw[BD1 + i] = bd1[i]; sw[WD2 + i] = Wd2[i]; }
    if (t == 0) {
      sw[BD2] = bd2[0];
      sw[BC2 + 0] = bc2[0]; sw[BC2 + 1] = bc2[1]; sw[BC2 + 2] = bc2[2];
    }
    if (t < 32) {
      sw[NV4 + t * 4 + 0] = bc1[t];
      sw[NV4 + t * 4 + 1] = Wc1[32 * 32 + t];
      sw[NV4 + t * 4 + 2] = Wc1[33 * 32 + t];
      sw[NV4 + t * 4 + 3] = Wc1[34 * 32 + t];
      sw[W24 + t * 4 + 0] = Wc2[t * 3 + 0];
      sw[W24 + t * 4 + 1] = Wc2[t * 3 + 1];
      sw[W24 + t * 4 + 2] = Wc2[t * 3 + 2];
      sw[W24 + t * 4 + 3] = 0.0f;
    }
  }

  // ---- ray setup (block-uniform) ----
  const float k00 = K[0], k01 = K[1], k02 = K[2];
  const float k10 = K[3], k11 = K[4], k12 = K[5];
  const float k20 = K[6], k21 = K[7], k22 = K[8];
  const float det = k00 * (k11 * k22 - k12 * k21)
                  - k01 * (k10 * k22 - k12 * k20)
                  + k02 * (k10 * k21 - k11 * k20);
  const float id = 1.0f / det;
  const float i00 =  (k11 * k22 - k12 * k21) * id;
  const float i01 = -(k01 * k22 - k02 * k21) * id;
  const float i02 =  (k01 * k12 - k02 * k11) * id;
  const float i10 = -(k10 * k22 - k12 * k20) * id;
  const float i11 =  (k00 * k22 - k02 * k20) * id;
  const float i12 = -(k00 * k12 - k02 * k10) * id;
  const float i20 =  (k10 * k21 - k11 * k20) * id;
  const float i21 = -(k00 * k21 - k01 * k20) * id;
  const float i22 =  (k00 * k11 - k01 * k10) * id;

  const float dwx = ww[ray] + 0.5f;
  const float dwy = hh[ray] + 0.5f;
  const float cx = i00 * dwx + i01 * dwy + i02;
  const float cy = i10 * dwx + i11 * dwy + i12;
  const float cz = i20 * dwx + i21 * dwy + i22;
  const float* Er = E + (size_t)ray * 16;
  const float ox = Er[3], oy = Er[7], oz = Er[11];
  const float dx = Er[0] * cx + Er[1] * cy + Er[2] * cz;
  const float dy = Er[4] * cx + Er[5] * cy + Er[6] * cz;
  const float dz = Er[8] * cx + Er[9] * cy + Er[10] * cz;
  const float dd = dx * dx + dy * dy + dz * dz;
  const float inv_nrm = fast_rsq(dd);
  const float ndx = dx * inv_nrm, ndy = dy * inv_nrm, ndz = dz * inv_nrm;
  // quadratic-expansion constants for dist^2 = |o + d z|^2
  const float oo  = ox * ox + oy * oy + oz * oz;
  const float od2 = 2.0f * (ox * dx + oy * dy + oz * dz);

  // A_n = o . Wd1[:,n], B_n = d . Wd1[:,n]  (per-ray, 32 threads, reads global Wd1)
  if (t < 32) {
    const float w0 = Wd1[t], w1 = Wd1[32 + t], w2 = Wd1[64 + t];
    s_A[t] = ox * w0 + oy * w1 + oz * w2;
    s_B[t] = dx * w0 + dy * w1 + dz * w2;
  }

  __syncthreads();   // weights + A/B staged

  // ---- coarse pass: e0 = t (all threads); e1 = 128+t (wave 0 only, FUSED loop) ----
  // h_n = relu(ms * A_n + msz * B_n + b_n), ms = mip scale, msz = ms*z
  const float bd2v = sw[BD2];
  float a0, v0, a1e = 0.0f, v1e = 1.0f;
  {
    float ms0, msz0, ms1 = 0.f, msz1 = 0.f;
    {
      const float z = exp10_f(zlog_c(t));
      const float d2 = fmaf(z, fmaf(z, dd, od2), oo);
      const float r = fast_rsq(fmaxf(d2, 1.0f));
      ms0 = (2.0f - r) * r;
      msz0 = ms0 * z;
    }
    if (wv == 0) {
      const float z = exp10_f((float)t * 0.015625f);   // zlog_c(128+t)
      const float d2 = fmaf(z, fmaf(z, dd, od2), oo);
      const float r = fast_rsq(fmaxf(d2, 1.0f));
      ms1 = (2.0f - r) * r;
      msz1 = ms1 * z;
    }
    float acc0 = bd2v, acc1 = bd2v;
    if (wv == 0) {  // wave-uniform branch: fused 2-sample loop (coeffs loaded once)
#pragma unroll 2
      for (int c = 0; c < 8; ++c) {
        const int k4 = c * 4;
        const float4 A  = ldsf4(s_A + k4);
        const float4 B  = ldsf4(s_B + k4);
        const float4 b  = ldsf4(sw + BD1 + k4);
        const float4 wd = ldsf4(sw + WD2 + k4);
        float v;
        v = fmaf(msz0, B.x, fmaf(ms0, A.x, b.x)); acc0 += fmaxf(v, 0.0f) * wd.x;
        v = fmaf(msz0, B.y, fmaf(ms0, A.y, b.y)); acc0 += fmaxf(v, 0.0f) * wd.y;
        v = fmaf(msz0, B.z, fmaf(ms0, A.z, b.z)); acc0 += fmaxf(v, 0.0f) * wd.z;
        v = fmaf(msz0, B.w, fmaf(ms0, A.w, b.w)); acc0 += fmaxf(v, 0.0f) * wd.w;
        v = fmaf(msz1, B.x, fmaf(ms1, A.x, b.x)); acc1 += fmaxf(v, 0.0f) * wd.x;
        v = fmaf(msz1, B.y, fmaf(ms1, A.y, b.y)); acc1 += fmaxf(v, 0.0f) * wd.y;
        v = fmaf(msz1, B.z, fmaf(ms1, A.z, b.z)); acc1 += fmaxf(v, 0.0f) * wd.z;
        v = fmaf(msz1, B.w, fmaf(ms1, A.w, b.w)); acc1 += fmaxf(v, 0.0f) * wd.w;
      }
    } else {
#pragma unroll 2
      for (int c = 0; c < 8; ++c) {
        const int k4 = c * 4;
        const float4 A  = ldsf4(s_A + k4);
        const float4 B  = ldsf4(s_B + k4);
        const float4 b  = ldsf4(sw + BD1 + k4);
        const float4 wd = ldsf4(sw + WD2 + k4);
        float v;
        v = fmaf(msz0, B.x, fmaf(ms0, A.x, b.x)); acc0 += fmaxf(v, 0.0f) * wd.x;
        v = fmaf(msz0, B.y, fmaf(ms0, A.y, b.y)); acc0 += fmaxf(v, 0.0f) * wd.y;
        v = fmaf(msz0, B.z, fmaf(ms0, A.z, b.z)); acc0 += fmaxf(v, 0.0f) * wd.z;
        v = fmaf(msz0, B.w, fmaf(ms0, A.w, b.w)); acc0 += fmaxf(v, 0.0f) * wd.w;
      }
    }
    v0 = __expf(-softplus_f(acc0) * delta_c(t));
    a0 = 1.0f - v0;
    if (wv == 0) {
      v1e = __expf(-softplus_f(acc1) * delta_c(128 + t));
      a1e = 1.0f - v1e;
    }
  }

  // parallel cumprod of (1-alpha)
  float i0 = wave_scan_mul(v0, lane);
  float i1 = 1.0f;
  if (wv == 0) i1 = wave_scan_mul(v1e, lane);
  if (lane == 63) s_tot[wv] = i0;
  if (wv == 0 && lane == 63) s_tot[2] = i1;
  __syncthreads();
  {
    const float preC1 = s_tot[0];
    const float preC2 = s_tot[0] * s_tot[1];
    float e0x = __shfl_up(i0, 1, 64); if (lane == 0) e0x = 1.0f;
    s_w[t] = a0 * e0x * (wv ? preC1 : 1.0f);
    if (wv == 0) {
      float e1x = __shfl_up(i1, 1, 64); if (lane == 0) e1x = 1.0f;
      s_w[128 + t] = a1e * e1x * preC2;
    }
  }
  __syncthreads();

  // reweight
  float wre0, wre1 = 0.0f;
  {
    const float wm = (t > 0) ? s_w[t - 1] : 0.0f;
    const float w0 = s_w[t];
    const float wp = s_w[t + 1];
    wre0 = 0.5f * (fmaxf(wm, w0) + fmaxf(w0, wp)) + (0.02f / 192.0f);
    wre0 *= (t < 128) ? (128.0f / 192.0f) : (64.0f / 192.0f);
  }
  if (wv == 0) {
    const int e = 128 + t;
    const float wm = s_w[e - 1];
    const float w0 = s_w[e];
    const float wp = (e < SC - 1) ? s_w[e + 1] : 0.0f;
    wre1 = 0.5f * (fmaxf(wm, w0) + fmaxf(w0, wp)) + (0.02f / 192.0f);
    wre1 *= (64.0f / 192.0f);
  }

  // parallel cumsum -> normalized CDF
  float s0 = wave_scan_add(wre0, lane);
  float s1 = 0.0f;
  if (wv == 0) s1 = wave_scan_add(wre1, lane);
  if (lane == 63) s_tot[4 + wv] = s0;
  if (wv == 0 && lane == 63) s_tot[6] = s1;
  __syncthreads();
  {
    const float T0 = s_tot[4], T1 = s_tot[5], T2 = s_tot[6];
    const float inv_total = fast_rcp(T0 + T1 + T2);
    s_cdf[t] = (s0 + (wv ? T0 : 0.0f)) * inv_total;
    if (wv == 0) s_cdf[128 + t] = (s1 + T0 + T1) * inv_total;
  }
  __syncthreads();

  // ---- importance sampling ----
  float zlf, zf;
  {
    const uint32_t total = (uint32_t)n_rays * 128u;
    const uint32_t halfc = total >> 1;
    const uint32_t j = (uint32_t)ray * 128u + (uint32_t)t;
    uint32_t x0, x1;
    const bool first = (j < halfc);
    if (first) { x0 = j; x1 = j + halfc; } else { x0 = j - halfc; x1 = j; }
    threefry2x32_k42(x0, x1);
    const uint32_t bits = first ? x0 : x1;
    const float fr = __uint_as_float((bits >> 9) | 0x3f800000u) - 1.0f;

    float u = (float)t * 0.0078125f + fr * 0.0078125f;
    u = u * (s_cdf[190] - s_cdf[1]) + s_cdf[1];

    int lo = 0, hi = 189;
    while (lo < hi) {
      const int mid = (lo + hi) >> 1;
      if (s_cdf[1 + mid] <= u) lo = mid + 1; else hi = mid;
    }
    const int inds = lo + 1;
    const float cb = s_cdf[inds - 1], ca = s_cdf[inds];
    const float tt = (u - cb) * fast_rcp(ca - cb);
    const float zb = 0.5f * (zlog_c(inds - 1) + zlog_c(inds));
    const float za = 0.5f * (zlog_c(inds) + zlog_c(inds + 1));
    zlf = zb + (za - zb) * tt;
    s_zlf[t] = zlf;
    zf = exp10_f(zlf);
  }
  __syncthreads();   // last s_cdf read — union area now free for s_hf

  // ---- Wc1 A-frags (fp16, hi only) ----
  half8 Whi0, Whi1;
  if constexpr (USE_WS) {
    const uint4* frag = (const uint4*)((const char*)wsf + WS_FRAG_OFF);
    uint4 q0 = frag[lane * 2 + 0];
    uint4 q1 = frag[lane * 2 + 1];
    __builtin_memcpy(&Whi0, &q0, 16);
    __builtin_memcpy(&Whi1, &q1, 16);
  } else {
#pragma unroll
    for (int nt = 0; nt < 2; ++nt) {
      const int n_s = nt * 16 + (lane & 15);
      uint32_t hw[4];
#pragma unroll
      for (int j2 = 0; j2 < 4; ++j2) {
        const int k = quad * 8 + j2 * 2;
        hw[j2] = (uint32_t)f2h(Wc1[k * 32 + n_s])
               | ((uint32_t)f2h(Wc1[(k + 1) * 32 + n_s]) << 16);
      }
      uint4 q = make_uint4(hw[0], hw[1], hw[2], hw[3]);
      if (nt == 0) __builtin_memcpy(&Whi0, &q, 16);
      else         __builtin_memcpy(&Whi1, &q, 16);
    }
  }

  // ---- fine density per-thread (factorized); h -> LDS as fp16 (HW pack) ----
  float sigf;
  {
    const float d2 = fmaf(zf, fmaf(zf, dd, od2), oo);
    const float r = fast_rsq(fmaxf(d2, 1.0f));
    const float msf = (2.0f - r) * r;
    const float mszf = msf * zf;
    float sig_acc = bd2v;
    uint4 tmp;
#pragma unroll
    for (int c = 0; c < 8; ++c) {
      const int k4 = c * 4;
      const float4 A  = ldsf4(s_A + k4);
      const float4 B  = ldsf4(s_B + k4);
      const float4 b  = ldsf4(sw + BD1 + k4);
      const float4 wd = ldsf4(sw + WD2 + k4);
      float h0 = fmaxf(fmaf(mszf, B.x, fmaf(msf, A.x, b.x)), 0.0f);
      float h1 = fmaxf(fmaf(mszf, B.y, fmaf(msf, A.y, b.y)), 0.0f);
      float h2 = fmaxf(fmaf(mszf, B.z, fmaf(msf, A.z, b.z)), 0.0f);
      float h3 = fmaxf(fmaf(mszf, B.w, fmaf(msf, A.w, b.w)), 0.0f);
      sig_acc += h0 * wd.x + h1 * wd.y + h2 * wd.z + h3 * wd.w;
      const uint32_t pA = pk2h(h0, h1), pB = pk2h(h2, h3);
      if ((c & 1) == 0) { tmp.x = pA; tmp.y = pB; }
      else {
        tmp.z = pA; tmp.w = pB;
        *(uint4*)(s_hf + t * HSTRIDE + (c >> 1) * 8) = tmp;
      }
    }
    sigf = softplus_f(sig_acc);
  }
  __syncthreads();   // h staged for MFMA

  // ---- fine color via MFMA: a1^T[32 x 128] = Wc1^T . H^T (fp16) ----
  {
    // per-lane n-values from packed NV4/W24 tables (b128 reads)
    float dvv[2][4], w2v[2][4][3];
#pragma unroll
    for (int nt = 0; nt < 2; ++nt)
#pragma unroll
      for (int r = 0; r < 4; ++r) {
        const int n = nt * 16 + quad * 4 + r;
        const float4 nv = ldsf4(sw + NV4 + n * 4);
        dvv[nt][r] = nv.x + ndx * nv.y + ndy * nv.z + ndz * nv.w;
        const float4 w2 = ldsf4(sw + W24 + n * 4);
        w2v[nt][r][0] = w2.x; w2v[nt][r][1] = w2.y; w2v[nt][r][2] = w2.z;
      }

#pragma unroll
    for (int mt = 0; mt < 4; ++mt) {
      const int sbase = wv * 64 + mt * 16;
      const int srow = sbase + (lane & 15);
      const half8 Hf = *(const half8*)(s_hf + srow * HSTRIDE + quad * 8);

      f32x4 acc0 = {0.f, 0.f, 0.f, 0.f}, acc1 = {0.f, 0.f, 0.f, 0.f};
      acc0 = __builtin_amdgcn_mfma_f32_16x16x32_f16(Whi0, Hf, acc0, 0, 0, 0);
      acc1 = __builtin_amdgcn_mfma_f32_16x16x32_f16(Whi1, Hf, acc1, 0, 0, 0);

      float pc0 = 0.f, pc1 = 0.f, pc2 = 0.f;
#pragma unroll
      for (int r = 0; r < 4; ++r) {
        const float av0 = fmaxf(acc0[r] + dvv[0][r], 0.0f);
        const float av1 = fmaxf(acc1[r] + dvv[1][r], 0.0f);
        pc0 += av0 * w2v[0][r][0] + av1 * w2v[1][r][0];
        pc1 += av0 * w2v[0][r][1] + av1 * w2v[1][r][1];
        pc2 += av0 * w2v[0][r][2] + av1 * w2v[1][r][2];
      }
#pragma unroll
      for (int mask = 16; mask < 64; mask <<= 1) {
        pc0 += __shfl_xor(pc0, mask, 64);
        pc1 += __shfl_xor(pc1, mask, 64);
        pc2 += __shfl_xor(pc2, mask, 64);
      }
      const int cidx = lane >> 4;
      const float oc = (cidx == 0) ? pc0 : ((cidx == 1) ? pc1 : pc2);
      if (lane < 48) {
        const int s = sbase + (lane & 15);
        const float o = oc + sw[BC2 + cidx];
        s_rgb[s * RGBS + cidx] = fast_rcp(1.0f + __expf(-o));
      }
    }
  }

  // ---- fine alpha + parallel cumprod over 128 ----
  const float deltaf = (t < SF - 1) ? (s_zlf[t + 1] - zlf) : 0.0f;
  const float vf = __expf(-sigf * deltaf);
  const float af = 1.0f - vf;
  float fi = wave_scan_mul(vf, lane);
  if (lane == 63) s_tot[wv] = fi;
  __syncthreads();   // also makes s_rgb visible
  float efx = __shfl_up(fi, 1, 64); if (lane == 0) efx = 1.0f;
  const float wf = af * efx * (wv ? s_tot[0] : 1.0f);

  // ---- outputs ----
  float* o_img = out;
  float* o_w   = out + (size_t)n_rays * 3;
  float* o_z   = out + (size_t)n_rays * (3 + 128);
  float* o_inv = out + (size_t)n_rays * (3 + 256);

  o_w[(size_t)ray * 128 + t] = wf;
  o_z[(size_t)ray * 128 + t] = (zlf + 1.0f) * 0.5f;

  float r0 = wf * s_rgb[t * RGBS + 0];
  float r1 = wf * s_rgb[t * RGBS + 1];
  float r2 = wf * s_rgb[t * RGBS + 2];
  float r3 = wf, r4 = wf * fast_rcp(zf);
#pragma unroll
  for (int d = 32; d > 0; d >>= 1) {
    r0 += __shfl_down(r0, d, 64);
    r1 += __shfl_down(r1, d, 64);
    r2 += __shfl_down(r2, d, 64);
    r3 += __shfl_down(r3, d, 64);
    r4 += __shfl_down(r4, d, 64);
  }
  if (lane == 0) {
    float* p = &s_red[wv * 5];
    p[0] = r0; p[1] = r1; p[2] = r2; p[3] = r3; p[4] = r4;
  }
  __syncthreads();
  if (t == 0) {
    const float accw = s_red[3] + s_red[8];
    const float bgw = 1.0f - accw;
    o_img[(size_t)ray * 3 + 0] = (s_red[0] + s_red[5]) + bgw * bg[0];
    o_img[(size_t)ray * 3 + 1] = (s_red[1] + s_red[6]) + bgw * bg[1];
    o_img[(size_t)ray * 3 + 2] = (s_red[2] + s_red[7]) + bgw * bg[2];
    o_inv[ray] = s_red[4] + s_red[9];
  }
}

extern "C" void kernel_launch(void* const* d_in, const int* in_sizes, int n_in,
                              void* d_out, int out_size, void* d_ws, size_t ws_size,
                              hipStream_t stream) {
  const float* h   = (const float*)d_in[1];
  const float* w   = (const float*)d_in[2];
  const float* K   = (const float*)d_in[3];
  const float* E   = (const float*)d_in[4];
  const float* bg  = (const float*)d_in[5];
  const float* Wd1 = (const float*)d_in[6];
  const float* bd1 = (const float*)d_in[7];
  const float* Wd2 = (const float*)d_in[8];
  const float* bd2 = (const float*)d_in[9];
  const float* Wc1 = (const float*)d_in[10];
  const float* bc1 = (const float*)d_in[11];
  const float* Wc2 = (const float*)d_in[12];
  const float* bc2 = (const float*)d_in[13];
  const int n_rays = in_sizes[1];
  float* wsf = (float*)d_ws;

  if (ws_size >= WS_NEED) {
    pack_weights<<<1, NT, 0, stream>>>(Wd1, bd1, Wd2, bd2, Wc1, bc1, Wc2, bc2, wsf);
    nerf_fwd<true><<<n_rays, NT, 0, stream>>>(h, w, K, E, bg, Wd1, bd1, Wd2, bd2,
                                              Wc1, bc1, Wc2, bc2, wsf,
                                              (float*)d_out, n_rays);
  } else {
    nerf_fwd<false><<<n_rays, NT, 0, stream>>>(h, w, K, E, bg, Wd1, bd1, Wd2, bd2,
                                               Wc1, bc1, Wc2, bc2, nullptr,
                                               (float*)d_out, n_rays);
  }
}

// Round 2
// 78.661 us; speedup vs baseline: 1.1589x; 1.0344x over previous
//
#include <hip/hip_runtime.h>
#include <stdint.h>

#define SC 192      // coarse samples (128 + 64)
#define SF 128      // fine (importance) samples
#define NT 128      // threads per block = 2 waves

// LDS weight-image offsets (floats)
#define WD1   0     // 96  (3x32 row-major) -- DEAD after staging; overlaid by s_dv[32] at runtime
#define BD1   96    // 32
#define WD2   128   // 32
#define BD2   160   // 1
#define BC2   161   // 3
#define NV4   164   // 32 x float4: (bc1[n], Wc1[32][n], Wc1[33][n], Wc1[34][n])
#define W24   292   // 12 x uint4: compact Wc2 fp16 A-frags, idx = quad*3 + channel
#define SWTOT 420   // floats (105 float4s)

#define WS_FRAG_OFF 2048    // byte offset of Wc1 fp16 A-frags in d_ws
#define WS_NEED     4096

#define HSTRIDE 40  // ushort stride for H rows (80 B rows -> bank-friendly, 16B-aligned)
#define RGBS 4

using half8 = __attribute__((ext_vector_type(8))) _Float16;
using f32x4 = __attribute__((ext_vector_type(4))) float;

__device__ __forceinline__ float zlog_c(int t) {
  return (t < 128) ? (-1.0f + (float)t * 0.0078125f)
                   : ((float)(t - 128) * 0.015625f);
}
__device__ __forceinline__ float delta_c(int t) {
  if (t >= SC - 1) return 0.0f;
  return zlog_c(t + 1) - zlog_c(t);
}

__device__ __forceinline__ float fast_rcp(float x) { return __builtin_amdgcn_rcpf(x); }
__device__ __forceinline__ float fast_rsq(float x) { return __builtin_amdgcn_rsqf(x); }
__device__ __forceinline__ float exp10_f(float x) { return __expf(x * 2.30258509299f); }
__device__ __forceinline__ float softplus_f(float x) {
  return fmaxf(x, 0.0f) + __logf(1.0f + __expf(-fabsf(x)));
}

// fp16 helpers: pk2h = 1 HW instr (v_cvt_pkrtz_f16_f32); f2h = RTN scalar convert
__device__ __forceinline__ uint32_t pk2h(float a, float b) {
  auto p = __builtin_amdgcn_cvt_pkrtz(a, b);
  uint32_t u; __builtin_memcpy(&u, &p, 4); return u;
}
__device__ __forceinline__ unsigned short f2h(float f) {
  _Float16 h = (_Float16)f;
  unsigned short us; __builtin_memcpy(&us, &h, 2); return us;
}

__device__ __forceinline__ float4 ldsf4(const float* p) { return *(const float4*)p; }

// JAX threefry2x32 with key = (0, 42)
__device__ __forceinline__ void threefry2x32_k42(uint32_t& x0, uint32_t& x1) {
  const uint32_t ks0 = 0u, ks1 = 42u;
  const uint32_t ks2 = ks0 ^ ks1 ^ 0x1BD11BDAu;
  const uint32_t ks[3] = {ks0, ks1, ks2};
  const int rot[2][4] = {{13, 15, 26, 6}, {17, 29, 16, 24}};
  x0 += ks[0];
  x1 += ks[1];
#pragma unroll
  for (int i = 0; i < 5; ++i) {
#pragma unroll
    for (int j = 0; j < 4; ++j) {
      x0 += x1;
      const int r = rot[i & 1][j];
      x1 = (x1 << r) | (x1 >> (32 - r));
      x1 ^= x0;
    }
    x0 += ks[(i + 1) % 3];
    x1 += ks[(i + 2) % 3] + (uint32_t)(i + 1);
  }
}

__device__ __forceinline__ float wave_scan_mul(float v, int lane) {
#pragma unroll
  for (int d = 1; d < 64; d <<= 1) {
    float o = __shfl_up(v, d, 64);
    if (lane >= d) v *= o;
  }
  return v;
}
__device__ __forceinline__ float wave_scan_add(float v, int lane) {
#pragma unroll
  for (int d = 1; d < 64; d <<= 1) {
    float o = __shfl_up(v, d, 64);
    if (lane >= d) v += o;
  }
  return v;
}

// ---- pre-pack kernel: weight image + fp16 Wc1 A-frags (identical for all blocks) ----
__global__ __launch_bounds__(NT) void pack_weights(
    const float* __restrict__ Wd1, const float* __restrict__ bd1,
    const float* __restrict__ Wd2, const float* __restrict__ bd2,
    const float* __restrict__ Wc1, const float* __restrict__ bc1,
    const float* __restrict__ Wc2, const float* __restrict__ bc2,
    float* __restrict__ wsf) {
  const int t = threadIdx.x;
  for (int i = t; i < 96; i += NT) wsf[WD1 + i] = Wd1[i];
  for (int i = t; i < 32; i += NT) { wsf[BD1 + i] = bd1[i]; wsf[WD2 + i] = Wd2[i]; }
  if (t == 0) {
    wsf[BD2] = bd2[0];
    wsf[BC2 + 0] = bc2[0]; wsf[BC2 + 1] = bc2[1]; wsf[BC2 + 2] = bc2[2];
  }
  if (t < 32) {
    wsf[NV4 + t * 4 + 0] = bc1[t];
    wsf[NV4 + t * 4 + 1] = Wc1[32 * 32 + t];
    wsf[NV4 + t * 4 + 2] = Wc1[33 * 32 + t];
    wsf[NV4 + t * 4 + 3] = Wc1[34 * 32 + t];
  }
  // compact Wc2 fp16 A-frags for MFMA2 (16x16x32): A[m=channel][k=n]
  // entry idx = q*3 + m (q = k-quad, m = channel 0..2): 8 halves = uint4
  if (t < 12) {
    const int m = t % 3, q = t / 3;
    uint32_t hw[4];
#pragma unroll
    for (int j2 = 0; j2 < 4; ++j2) {
      const int k0 = q * 8 + j2 * 2;
      hw[j2] = (uint32_t)f2h(Wc2[k0 * 3 + m])
             | ((uint32_t)f2h(Wc2[(k0 + 1) * 3 + m]) << 16);
    }
    ((uint4*)(wsf + W24))[t] = make_uint4(hw[0], hw[1], hw[2], hw[3]);
  }
  // Wc1[0:32][:] fp16 A-frags: frag[lane*2 + nt]; A[m=n][k], lane: n=nt*16+(lane&15), k=quad*8+j
  if (t < 64) {
    const int q_s = t >> 4;
    uint4* frag = (uint4*)((char*)wsf + WS_FRAG_OFF);
#pragma unroll
    for (int nt = 0; nt < 2; ++nt) {
      const int n_s = nt * 16 + (t & 15);
      uint32_t hw[4];
#pragma unroll
      for (int j2 = 0; j2 < 4; ++j2) {
        const int k = q_s * 8 + j2 * 2;
        hw[j2] = (uint32_t)f2h(Wc1[k * 32 + n_s])
               | ((uint32_t)f2h(Wc1[(k + 1) * 32 + n_s]) << 16);
      }
      frag[t * 2 + nt] = make_uint4(hw[0], hw[1], hw[2], hw[3]);
    }
  }
}

template <bool USE_WS>
__global__ __launch_bounds__(NT) void nerf_fwd(
    const float* __restrict__ hh, const float* __restrict__ ww,
    const float* __restrict__ K, const float* __restrict__ E,
    const float* __restrict__ bg,
    const float* __restrict__ Wd1, const float* __restrict__ bd1,
    const float* __restrict__ Wd2, const float* __restrict__ bd2,
    const float* __restrict__ Wc1, const float* __restrict__ bc1,
    const float* __restrict__ Wc2, const float* __restrict__ bc2,
    const float* __restrict__ wsf,
    float* __restrict__ out, int n_rays) {
  const int ray = blockIdx.x;
  const int t = threadIdx.x;
  const int lane = t & 63;
  const int wv = t >> 6;   // 0 or 1
  const int quad = lane >> 4;

  __shared__ __align__(16) float sw[SWTOT];
  // per-ray factorized density-MLP coefficients: A = o@Wd1, B = d@Wd1
  __shared__ __align__(16) float s_A[32];
  __shared__ __align__(16) float s_B[32];
  // phase-union: coarse {s_w, s_cdf} then fine H (fp16), then av (fp16, row-recycled)
  __shared__ __align__(16) unsigned char u_buf[SF * HSTRIDE * 2];  // 10240 B
  float* const s_w   = (float*)u_buf;
  float* const s_cdf = (float*)(u_buf + 768);
  unsigned short* const s_hf = (unsigned short*)u_buf;
  __shared__ float s_rgb[SF * RGBS];
  __shared__ float s_zlf[SF];
  __shared__ float s_tot[8];
  __shared__ float s_red[16];
  float* const s_dv = sw;   // overlay on dead WD1 region (never read after staging)

  // ---- stage weight image into LDS ----
  if constexpr (USE_WS) {
    const float4* wsrc = (const float4*)wsf;
    float4* sdst = (float4*)sw;
    for (int i = t; i < SWTOT / 4; i += NT) sdst[i] = wsrc[i];
  } else {
    for (int i = t; i < 96; i += NT) sw[WD1 + i] = Wd1[i];
    for (int i = t; i < 32; i += NT) { sw[BD1 + i] = bd1[i]; sw[WD2 + i] = Wd2[i]; }
    if (t == 0) {
      sw[BD2] = bd2[0];
      sw[BC2 + 0] = bc2[0]; sw[BC2 + 1] = bc2[1]; sw[BC2 + 2] = bc2[2];
    }
    if (t < 32) {
      sw[NV4 + t * 4 + 0] = bc1[t];
      sw[NV4 + t * 4 + 1] = Wc1[32 * 32 + t];
      sw[NV4 + t * 4 + 2] = Wc1[33 * 32 + t];
      sw[NV4 + t * 4 + 3] = Wc1[34 * 32 + t];
    }
    if (t < 12) {
      const int m = t % 3, q = t / 3;
      uint32_t hw[4];
#pragma unroll
      for (int j2 = 0; j2 < 4; ++j2) {
        const int k0 = q * 8 + j2 * 2;
        hw[j2] = (uint32_t)f2h(Wc2[k0 * 3 + m])
               | ((uint32_t)f2h(Wc2[(k0 + 1) * 3 + m]) << 16);
      }
      ((uint4*)(sw + W24))[t] = make_uint4(hw[0], hw[1], hw[2], hw[3]);
    }
  }

  // ---- ray setup (block-uniform) ----
  const float k00 = K[0], k01 = K[1], k02 = K[2];
  const float k10 = K[3], k11 = K[4], k12 = K[5];
  const float k20 = K[6], k21 = K[7], k22 = K[8];
  const float det = k00 * (k11 * k22 - k12 * k21)
                  - k01 * (k10 * k22 - k12 * k20)
                  + k02 * (k10 * k21 - k11 * k20);
  const float id = 1.0f / det;
  const float i00 =  (k11 * k22 - k12 * k21) * id;
  const float i01 = -(k01 * k22 - k02 * k21) * id;
  const float i02 =  (k01 * k12 - k02 * k11) * id;
  const float i10 = -(k10 * k22 - k12 * k20) * id;
  const float i11 =  (k00 * k22 - k02 * k20) * id;
  const float i12 = -(k00 * k12 - k02 * k10) * id;
  const float i20 =  (k10 * k21 - k11 * k20) * id;
  const float i21 = -(k00 * k21 - k01 * k20) * id;
  const float i22 =  (k00 * k11 - k01 * k10) * id;

  const float dwx = ww[ray] + 0.5f;
  const float dwy = hh[ray] + 0.5f;
  const float cx = i00 * dwx + i01 * dwy + i02;
  const float cy = i10 * dwx + i11 * dwy + i12;
  const float cz = i20 * dwx + i21 * dwy + i22;
  const float* Er = E + (size_t)ray * 16;
  const float ox = Er[3], oy = Er[7], oz = Er[11];
  const float dx = Er[0] * cx + Er[1] * cy + Er[2] * cz;
  const float dy = Er[4] * cx + Er[5] * cy + Er[6] * cz;
  const float dz = Er[8] * cx + Er[9] * cy + Er[10] * cz;
  const float dd = dx * dx + dy * dy + dz * dz;
  const float inv_nrm = fast_rsq(dd);
  const float ndx = dx * inv_nrm, ndy = dy * inv_nrm, ndz = dz * inv_nrm;
  // quadratic-expansion constants for dist^2 = |o + d z|^2
  const float oo  = ox * ox + oy * oy + oz * oz;
  const float od2 = 2.0f * (ox * dx + oy * dy + oz * dz);

  // A_n = o . Wd1[:,n], B_n = d . Wd1[:,n]  (per-ray, 32 threads, reads global Wd1)
  if (t < 32) {
    const float w0 = Wd1[t], w1 = Wd1[32 + t], w2 = Wd1[64 + t];
    s_A[t] = ox * w0 + oy * w1 + oz * w2;
    s_B[t] = dx * w0 + dy * w1 + dz * w2;
  }

  __syncthreads();   // weights + A/B staged

  // per-ray dv table: dv_n = bc1[n] + nd . Wc1[32:35][:,n]  (overlays dead WD1 region)
  if (t < 32) {
    const float4 nv = ldsf4(sw + NV4 + t * 4);
    s_dv[t] = nv.x + ndx * nv.y + ndy * nv.z + ndz * nv.w;
  }

  // ---- coarse pass: e0 = t (all threads); e1 = 128+t (wave 0 only, FUSED loop) ----
  // h_n = relu(ms * A_n + msz * B_n + b_n), ms = mip scale, msz = ms*z
  const float bd2v = sw[BD2];
  float a0, v0, a1e = 0.0f, v1e = 1.0f;
  {
    float ms0, msz0, ms1 = 0.f, msz1 = 0.f;
    {
      const float z = exp10_f(zlog_c(t));
      const float d2 = fmaf(z, fmaf(z, dd, od2), oo);
      const float r = fast_rsq(fmaxf(d2, 1.0f));
      ms0 = (2.0f - r) * r;
      msz0 = ms0 * z;
    }
    if (wv == 0) {
      const float z = exp10_f((float)t * 0.015625f);   // zlog_c(128+t)
      const float d2 = fmaf(z, fmaf(z, dd, od2), oo);
      const float r = fast_rsq(fmaxf(d2, 1.0f));
      ms1 = (2.0f - r) * r;
      msz1 = ms1 * z;
    }
    float acc0 = bd2v, acc1 = bd2v;
    if (wv == 0) {  // wave-uniform branch: fused 2-sample loop (coeffs loaded once)
#pragma unroll 2
      for (int c = 0; c < 8; ++c) {
        const int k4 = c * 4;
        const float4 A  = ldsf4(s_A + k4);
        const float4 B  = ldsf4(s_B + k4);
        const float4 b  = ldsf4(sw + BD1 + k4);
        const float4 wd = ldsf4(sw + WD2 + k4);
        float v;
        v = fmaf(msz0, B.x, fmaf(ms0, A.x, b.x)); acc0 += fmaxf(v, 0.0f) * wd.x;
        v = fmaf(msz0, B.y, fmaf(ms0, A.y, b.y)); acc0 += fmaxf(v, 0.0f) * wd.y;
        v = fmaf(msz0, B.z, fmaf(ms0, A.z, b.z)); acc0 += fmaxf(v, 0.0f) * wd.z;
        v = fmaf(msz0, B.w, fmaf(ms0, A.w, b.w)); acc0 += fmaxf(v, 0.0f) * wd.w;
        v = fmaf(msz1, B.x, fmaf(ms1, A.x, b.x)); acc1 += fmaxf(v, 0.0f) * wd.x;
        v = fmaf(msz1, B.y, fmaf(ms1, A.y, b.y)); acc1 += fmaxf(v, 0.0f) * wd.y;
        v = fmaf(msz1, B.z, fmaf(ms1, A.z, b.z)); acc1 += fmaxf(v, 0.0f) * wd.z;
        v = fmaf(msz1, B.w, fmaf(ms1, A.w, b.w)); acc1 += fmaxf(v, 0.0f) * wd.w;
      }
    } else {
#pragma unroll 2
      for (int c = 0; c < 8; ++c) {
        const int k4 = c * 4;
        const float4 A  = ldsf4(s_A + k4);
        const float4 B  = ldsf4(s_B + k4);
        const float4 b  = ldsf4(sw + BD1 + k4);
        const float4 wd = ldsf4(sw + WD2 + k4);
        float v;
        v = fmaf(msz0, B.x, fmaf(ms0, A.x, b.x)); acc0 += fmaxf(v, 0.0f) * wd.x;
        v = fmaf(msz0, B.y, fmaf(ms0, A.y, b.y)); acc0 += fmaxf(v, 0.0f) * wd.y;
        v = fmaf(msz0, B.z, fmaf(ms0, A.z, b.z)); acc0 += fmaxf(v, 0.0f) * wd.z;
        v = fmaf(msz0, B.w, fmaf(ms0, A.w, b.w)); acc0 += fmaxf(v, 0.0f) * wd.w;
      }
    }
    v0 = __expf(-softplus_f(acc0) * delta_c(t));
    a0 = 1.0f - v0;
    if (wv == 0) {
      v1e = __expf(-softplus_f(acc1) * delta_c(128 + t));
      a1e = 1.0f - v1e;
    }
  }

  // parallel cumprod of (1-alpha)
  float i0 = wave_scan_mul(v0, lane);
  float i1 = 1.0f;
  if (wv == 0) i1 = wave_scan_mul(v1e, lane);
  if (lane == 63) s_tot[wv] = i0;
  if (wv == 0 && lane == 63) s_tot[2] = i1;
  __syncthreads();
  {
    const float preC1 = s_tot[0];
    const float preC2 = s_tot[0] * s_tot[1];
    float e0x = __shfl_up(i0, 1, 64); if (lane == 0) e0x = 1.0f;
    s_w[t] = a0 * e0x * (wv ? preC1 : 1.0f);
    if (wv == 0) {
      float e1x = __shfl_up(i1, 1, 64); if (lane == 0) e1x = 1.0f;
      s_w[128 + t] = a1e * e1x * preC2;
    }
  }
  __syncthreads();

  // reweight
  float wre0, wre1 = 0.0f;
  {
    const float wm = (t > 0) ? s_w[t - 1] : 0.0f;
    const float w0 = s_w[t];
    const float wp = s_w[t + 1];
    wre0 = 0.5f * (fmaxf(wm, w0) + fmaxf(w0, wp)) + (0.02f / 192.0f);
    wre0 *= (t < 128) ? (128.0f / 192.0f) : (64.0f / 192.0f);
  }
  if (wv == 0) {
    const int e = 128 + t;
    const float wm = s_w[e - 1];
    const float w0 = s_w[e];
    const float wp = (e < SC - 1) ? s_w[e + 1] : 0.0f;
    wre1 = 0.5f * (fmaxf(wm, w0) + fmaxf(w0, wp)) + (0.02f / 192.0f);
    wre1 *= (64.0f / 192.0f);
  }

  // parallel cumsum -> normalized CDF
  float s0 = wave_scan_add(wre0, lane);
  float s1 = 0.0f;
  if (wv == 0) s1 = wave_scan_add(wre1, lane);
  if (lane == 63) s_tot[4 + wv] = s0;
  if (wv == 0 && lane == 63) s_tot[6] = s1;
  __syncthreads();
  {
    const float T0 = s_tot[4], T1 = s_tot[5], T2 = s_tot[6];
    const float inv_total = fast_rcp(T0 + T1 + T2);
    s_cdf[t] = (s0 + (wv ? T0 : 0.0f)) * inv_total;
    if (wv == 0) s_cdf[128 + t] = (s1 + T0 + T1) * inv_total;
  }
  __syncthreads();

  // ---- importance sampling ----
  float zlf, zf;
  {
    const uint32_t total = (uint32_t)n_rays * 128u;
    const uint32_t halfc = total >> 1;
    const uint32_t j = (uint32_t)ray * 128u + (uint32_t)t;
    uint32_t x0, x1;
    const bool first = (j < halfc);
    if (first) { x0 = j; x1 = j + halfc; } else { x0 = j - halfc; x1 = j; }
    threefry2x32_k42(x0, x1);
    const uint32_t bits = first ? x0 : x1;
    const float fr = __uint_as_float((bits >> 9) | 0x3f800000u) - 1.0f;

    float u = (float)t * 0.0078125f + fr * 0.0078125f;
    u = u * (s_cdf[190] - s_cdf[1]) + s_cdf[1];

    int lo = 0, hi = 189;
    while (lo < hi) {
      const int mid = (lo + hi) >> 1;
      if (s_cdf[1 + mid] <= u) lo = mid + 1; else hi = mid;
    }
    const int inds = lo + 1;
    const float cb = s_cdf[inds - 1], ca = s_cdf[inds];
    const float tt = (u - cb) * fast_rcp(ca - cb);
    const float zb = 0.5f * (zlog_c(inds - 1) + zlog_c(inds));
    const float za = 0.5f * (zlog_c(inds) + zlog_c(inds + 1));
    zlf = zb + (za - zb) * tt;
    s_zlf[t] = zlf;
    zf = exp10_f(zlf);
  }
  __syncthreads();   // last s_cdf read — union area now free for s_hf

  // ---- Wc1 A-frags (fp16, hi only) ----
  half8 Whi0, Whi1;
  if constexpr (USE_WS) {
    const uint4* frag = (const uint4*)((const char*)wsf + WS_FRAG_OFF);
    uint4 q0 = frag[lane * 2 + 0];
    uint4 q1 = frag[lane * 2 + 1];
    __builtin_memcpy(&Whi0, &q0, 16);
    __builtin_memcpy(&Whi1, &q1, 16);
  } else {
#pragma unroll
    for (int nt = 0; nt < 2; ++nt) {
      const int n_s = nt * 16 + (lane & 15);
      uint32_t hw[4];
#pragma unroll
      for (int j2 = 0; j2 < 4; ++j2) {
        const int k = quad * 8 + j2 * 2;
        hw[j2] = (uint32_t)f2h(Wc1[k * 32 + n_s])
               | ((uint32_t)f2h(Wc1[(k + 1) * 32 + n_s]) << 16);
      }
      uint4 q = make_uint4(hw[0], hw[1], hw[2], hw[3]);
      if (nt == 0) __builtin_memcpy(&Whi0, &q, 16);
      else         __builtin_memcpy(&Whi1, &q, 16);
    }
  }

  // ---- fine density per-thread (factorized); h -> LDS as fp16 (HW pack) ----
  float sigf;
  {
    const float d2 = fmaf(zf, fmaf(zf, dd, od2), oo);
    const float r = fast_rsq(fmaxf(d2, 1.0f));
    const float msf = (2.0f - r) * r;
    const float mszf = msf * zf;
    float sig_acc = bd2v;
    uint4 tmp;
#pragma unroll
    for (int c = 0; c < 8; ++c) {
      const int k4 = c * 4;
      const float4 A  = ldsf4(s_A + k4);
      const float4 B  = ldsf4(s_B + k4);
      const float4 b  = ldsf4(sw + BD1 + k4);
      const float4 wd = ldsf4(sw + WD2 + k4);
      float h0 = fmaxf(fmaf(mszf, B.x, fmaf(msf, A.x, b.x)), 0.0f);
      float h1 = fmaxf(fmaf(mszf, B.y, fmaf(msf, A.y, b.y)), 0.0f);
      float h2 = fmaxf(fmaf(mszf, B.z, fmaf(msf, A.z, b.z)), 0.0f);
      float h3 = fmaxf(fmaf(mszf, B.w, fmaf(msf, A.w, b.w)), 0.0f);
      sig_acc += h0 * wd.x + h1 * wd.y + h2 * wd.z + h3 * wd.w;
      const uint32_t pA = pk2h(h0, h1), pB = pk2h(h2, h3);
      if ((c & 1) == 0) { tmp.x = pA; tmp.y = pB; }
      else {
        tmp.z = pA; tmp.w = pB;
        *(uint4*)(s_hf + t * HSTRIDE + (c >> 1) * 8) = tmp;
      }
    }
    sigf = softplus_f(sig_acc);
  }
  __syncthreads();   // h staged for MFMA

  // ---- fine color via MFMA, both layers ----
  // layer1: a1[32 x 16] = Wc1^T . H^T per mt; av = relu(a1 + dv) -> fp16 back into
  //         the just-consumed s_hf rows ([sample][n] layout, same-wave DS ordering)
  // layer2: rgb_pre[3 x 16] = Wc2^T . av  via MFMA2 (A rows 0..2 = channels)
  {
    // hoisted per-wave: dv fragments + Wc2 A-frag + bc2
    const float4 dv0 = ldsf4(s_dv + quad * 4);
    const float4 dv1 = ldsf4(s_dv + 16 + quad * 4);
    const int m15 = lane & 15;
    uint4 qf = ((const uint4*)(sw + W24))[quad * 3 + (m15 < 3 ? m15 : 0)];
    if (m15 >= 3) qf = make_uint4(0u, 0u, 0u, 0u);
    half8 W2f; __builtin_memcpy(&W2f, &qf, 16);
    const float bc2x = sw[BC2 + 0], bc2y = sw[BC2 + 1], bc2z = sw[BC2 + 2];

#pragma unroll
    for (int mt = 0; mt < 4; ++mt) {
      const int sbase = wv * 64 + mt * 16;
      const int srow = sbase + m15;
      const half8 Hf = *(const half8*)(s_hf + srow * HSTRIDE + quad * 8);

      f32x4 acc0 = {0.f, 0.f, 0.f, 0.f}, acc1 = {0.f, 0.f, 0.f, 0.f};
      acc0 = __builtin_amdgcn_mfma_f32_16x16x32_f16(Whi0, Hf, acc0, 0, 0, 0);
      acc1 = __builtin_amdgcn_mfma_f32_16x16x32_f16(Whi1, Hf, acc1, 0, 0, 0);

      // av = relu(acc + dv), pack fp16, write to [srow][n] (rows just consumed)
      uint32_t w0[2], w1[2];
      w0[0] = pk2h(fmaxf(acc0[0] + dv0.x, 0.0f), fmaxf(acc0[1] + dv0.y, 0.0f));
      w0[1] = pk2h(fmaxf(acc0[2] + dv0.z, 0.0f), fmaxf(acc0[3] + dv0.w, 0.0f));
      w1[0] = pk2h(fmaxf(acc1[0] + dv1.x, 0.0f), fmaxf(acc1[1] + dv1.y, 0.0f));
      w1[1] = pk2h(fmaxf(acc1[2] + dv1.z, 0.0f), fmaxf(acc1[3] + dv1.w, 0.0f));
      __builtin_memcpy(s_hf + srow * HSTRIDE + quad * 4, w0, 8);
      __builtin_memcpy(s_hf + srow * HSTRIDE + 16 + quad * 4, w1, 8);
    }

    // layer2: 4 MFMAs cover this wave's 64 samples (same-wave DS order: avs are ready)
#pragma unroll
    for (int g = 0; g < 4; ++g) {
      const int scol = wv * 64 + g * 16 + m15;
      half8 Bav;
      __builtin_memcpy(&Bav, s_hf + scol * HSTRIDE + quad * 8, 16);
      f32x4 acc2 = {0.f, 0.f, 0.f, 0.f};
      acc2 = __builtin_amdgcn_mfma_f32_16x16x32_f16(W2f, Bav, acc2, 0, 0, 0);
      if (quad == 0) {
        float4 px;
        px.x = fast_rcp(1.0f + __expf(-(acc2[0] + bc2x)));
        px.y = fast_rcp(1.0f + __expf(-(acc2[1] + bc2y)));
        px.z = fast_rcp(1.0f + __expf(-(acc2[2] + bc2z)));
        px.w = 0.0f;
        *(float4*)(s_rgb + scol * RGBS) = px;
      }
    }
  }

  // ---- fine alpha + parallel cumprod over 128 ----
  const float deltaf = (t < SF - 1) ? (s_zlf[t + 1] - zlf) : 0.0f;
  const float vf = __expf(-sigf * deltaf);
  const float af = 1.0f - vf;
  float fi = wave_scan_mul(vf, lane);
  if (lane == 63) s_tot[wv] = fi;
  __syncthreads();   // also makes s_rgb / s_tot visible cross-wave
  float efx = __shfl_up(fi, 1, 64); if (lane == 0) efx = 1.0f;
  const float wf = af * efx * (wv ? s_tot[0] : 1.0f);

  // ---- outputs ----
  float* o_img = out;
  float* o_w   = out + (size_t)n_rays * 3;
  float* o_z   = out + (size_t)n_rays * (3 + 128);
  float* o_inv = out + (size_t)n_rays * (3 + 256);

  o_w[(size_t)ray * 128 + t] = wf;
  o_z[(size_t)ray * 128 + t] = (zlf + 1.0f) * 0.5f;

  const float4 rgbv = ldsf4(s_rgb + t * RGBS);
  float r0 = wf * rgbv.x;
  float r1 = wf * rgbv.y;
  float r2 = wf * rgbv.z;
  float r3 = wf, r4 = wf * fast_rcp(zf);
#pragma unroll
  for (int d = 32; d > 0; d >>= 1) {
    r0 += __shfl_down(r0, d, 64);
    r1 += __shfl_down(r1, d, 64);
    r2 += __shfl_down(r2, d, 64);
    r3 += __shfl_down(r3, d, 64);
    r4 += __shfl_down(r4, d, 64);
  }
  if (lane == 0) {
    float* p = &s_red[wv * 5];
    p[0] = r0; p[1] = r1; p[2] = r2; p[3] = r3; p[4] = r4;
  }
  __syncthreads();
  if (t == 0) {
    const float accw = s_red[3] + s_red[8];
    const float bgw = 1.0f - accw;
    o_img[(size_t)ray * 3 + 0] = (s_red[0] + s_red[5]) + bgw * bg[0];
    o_img[(size_t)ray * 3 + 1] = (s_red[1] + s_red[6]) + bgw * bg[1];
    o_img[(size_t)ray * 3 + 2] = (s_red[2] + s_red[7]) + bgw * bg[2];
    o_inv[ray] = s_red[4] + s_red[9];
  }
}

extern "C" void kernel_launch(void* const* d_in, const int* in_sizes, int n_in,
                              void* d_out, int out_size, void* d_ws, size_t ws_size,
                              hipStream_t stream) {
  const float* h   = (const float*)d_in[1];
  const float* w   = (const float*)d_in[2];
  const float* K   = (const float*)d_in[3];
  const float* E   = (const float*)d_in[4];
  const float* bg  = (const float*)d_in[5];
  const float* Wd1 = (const float*)d_in[6];
  const float* bd1 = (const float*)d_in[7];
  const float* Wd2 = (const float*)d_in[8];
  const float* bd2 = (const float*)d_in[9];
  const float* Wc1 = (const float*)d_in[10];
  const float* bc1 = (const float*)d_in[11];
  const float* Wc2 = (const float*)d_in[12];
  const float* bc2 = (const float*)d_in[13];
  const int n_rays = in_sizes[1];
  float* wsf = (float*)d_ws;

  if (ws_size >= WS_NEED) {
    pack_weights<<<1, NT, 0, stream>>>(Wd1, bd1, Wd2, bd2, Wc1, bc1, Wc2, bc2, wsf);
    nerf_fwd<true><<<n_rays, NT, 0, stream>>>(h, w, K, E, bg, Wd1, bd1, Wd2, bd2,
                                              Wc1, bc1, Wc2, bc2, wsf,
                                              (float*)d_out, n_rays);
  } else {
    nerf_fwd<false><<<n_rays, NT, 0, stream>>>(h, w, K, E, bg, Wd1, bd1, Wd2, bd2,
                                               Wc1, bc1, Wc2, bc2, nullptr,
                                               (float*)d_out, n_rays);
  }
}